// Round 6
// baseline (226.176 us; speedup 1.0000x reference)
//
#include <hip/hip_runtime.h>

typedef unsigned short u16;
typedef unsigned int u32;
typedef __bf16 bf16x8 __attribute__((ext_vector_type(8)));
typedef u16 u16x8 __attribute__((ext_vector_type(8)));
typedef float floatx4 __attribute__((ext_vector_type(4)));

#define MFMA16(a, b, c) __builtin_amdgcn_mfma_f32_16x16x32_bf16((a), (b), (c), 0, 0, 0)

#define B_ 2
#define S0 4096
#define NH 16
#define HD 64
#define HID 1024

__device__ __forceinline__ float bf2f(u16 u) {
  union { u32 i; float f; } x; x.i = ((u32)u) << 16; return x.f;
}
__device__ __forceinline__ u16 f2bf(float f) {
  union { float f; u32 i; } x; x.f = f;
  u32 r = x.i + 0x7FFFu + ((x.i >> 16) & 1u);
  return (u16)(r >> 16);
}

__device__ __forceinline__ void glds16(const u16* g, u16* l) {
  __builtin_amdgcn_global_load_lds(
      (const __attribute__((address_space(1))) u32*)g,
      (__attribute__((address_space(3))) u32*)l, 16, 0, 0);
}

// -------- fused prep: convert X, convert mask+biases, transpose weights -----
__global__ __launch_bounds__(256) void prep(
    const float* __restrict__ X, const float* __restrict__ mask,
    const float* __restrict__ Wq, const float* __restrict__ bq,
    const float* __restrict__ Wk, const float* __restrict__ bk,
    const float* __restrict__ Wv, const float* __restrict__ bv,
    const float* __restrict__ Wo, const float* __restrict__ bo,
    u16* __restrict__ cX, u16* __restrict__ cmask, u16* __restrict__ cb,
    u16* __restrict__ WqkvT, u16* __restrict__ WoT) {
  __shared__ u16 tile[64][66];
  int bid = blockIdx.x;
  if (bid < 4096) {                       // ---- X fp32 -> bf16 (8 elem/thr)
    int i = (bid * 256 + threadIdx.x) * 8;
    const float4* Xv = (const float4*)(X + i);
    float4 a = Xv[0], b = Xv[1];
    u16x8 v;
    v[0] = f2bf(a.x); v[1] = f2bf(a.y); v[2] = f2bf(a.z); v[3] = f2bf(a.w);
    v[4] = f2bf(b.x); v[5] = f2bf(b.y); v[6] = f2bf(b.z); v[7] = f2bf(b.w);
    *(u16x8*)(cX + i) = v;
  } else if (bid < 4144) {                // ---- mask + biases
    int tid = (bid - 4096) * 256 + threadIdx.x;
    if (tid < B_ * S0) {
      cmask[tid] = f2bf(mask[tid]);
    } else {
      int j = tid - B_ * S0;  // [0, 4096)
      int seg = j >> 10, idx = j & 1023;
      const float* src = (seg == 0) ? bq : (seg == 1) ? bk : (seg == 2) ? bv : bo;
      cb[seg * 1024 + idx] = f2bf(src[idx]);
    }
  } else {                                // ---- weight transpose (1024 blocks)
    int idx = bid - 4144;
    int mat = idx >> 8;
    const float* src = (mat == 0) ? Wq : (mat == 1) ? Wk : (mat == 2) ? Wv : Wo;
    u16* dst = (mat < 3) ? (WqkvT + (size_t)mat * HID * HID) : WoT;
    int t0 = ((idx >> 4) & 15) * 64;  // k base
    int c0 = (idx & 15) * 64;         // n base
    int tx = threadIdx.x & 63, ty = threadIdx.x >> 6;
#pragma unroll
    for (int i = 0; i < 16; i++) {
      int r = i * 4 + ty;
      tile[r][tx] = f2bf(src[(size_t)(t0 + r) * HID + c0 + tx]);
    }
    __syncthreads();
#pragma unroll
    for (int i = 0; i < 16; i++) {
      int r = i * 4 + ty;
      dst[(size_t)(c0 + r) * HID + t0 + tx] = tile[tx][r];
    }
  }
}

// ---------------- bf16 GEMM: C[m][n] = A[m][k] * Bt[n][k] + bias -----------
// BK=64, glds16 staging, 16B-chunk XOR swizzle -> conflict-free ds_read_b128.
// NMAJOR=1 (gemm0): x = n-tile so consecutive blocks share the A m-panel
// (L2-hot) -> measured 73.2 -> 66.0 us. NMAJOR=0 (gemm1): r0-proven m-major.
template <int BN, int MODE, int NMAJOR>
__global__ __launch_bounds__(256) void gemm_bf16_tn(
    const u16* __restrict__ A, const u16* __restrict__ Bt,
    const u16* __restrict__ cb, void* __restrict__ outp, int K) {
  constexpr int NT = BN / 32;  // 16-col tiles per wave (wave covers BN/2 cols)
  __shared__ alignas(16) u16 sA[128 * 64];
  __shared__ alignas(16) u16 sB[BN * 64];
  int t = threadIdx.x;
  int wave = t >> 6, lane = t & 63;
  int wm = wave >> 1, wn = wave & 1;
  int quad = lane >> 4, l16 = lane & 15;
  int tile_m = (NMAJOR ? blockIdx.y : blockIdx.x) * 128;
  int tile_n = (NMAJOR ? blockIdx.x : blockIdx.y) * BN;

  floatx4 acc[4][NT] = {};

  int row_l = lane >> 3;
  int col_l = ((lane & 7) ^ row_l) * 8;
  const u16* Ag = A + (size_t)(tile_m + wave * 8 + row_l) * K + col_l;
  const u16* Bg = Bt + (size_t)(tile_n + wave * 8 + row_l) * K + col_l;
  u16* lA = sA + wave * 8 * 64;
  u16* lB = sB + wave * 8 * 64;

  for (int k0 = 0; k0 < K; k0 += 64) {
    __syncthreads();
#pragma unroll
    for (int r = 0; r < 4; r++)
      glds16(Ag + (size_t)(r * 32) * K + k0, lA + r * 2048);
#pragma unroll
    for (int r = 0; r < BN / 32; r++)
      glds16(Bg + (size_t)(r * 32) * K + k0, lB + r * 2048);
    __syncthreads();

#pragma unroll
    for (int ks = 0; ks < 2; ks++) {
      bf16x8 af[4], bfr[NT];
#pragma unroll
      for (int mt = 0; mt < 4; mt++) {
        int row = wm * 64 + mt * 16 + l16;
        int p = (ks * 4 + quad) ^ (row & 7);
        af[mt] = *(const bf16x8*)(sA + row * 64 + p * 8);
      }
#pragma unroll
      for (int nt = 0; nt < NT; nt++) {
        int row = wn * (BN / 2) + nt * 16 + l16;
        int p = (ks * 4 + quad) ^ (row & 7);
        bfr[nt] = *(const bf16x8*)(sB + row * 64 + p * 8);
      }
#pragma unroll
      for (int mt = 0; mt < 4; mt++)
#pragma unroll
        for (int nt = 0; nt < NT; nt++)
          acc[mt][nt] = MFMA16(af[mt], bfr[nt], acc[mt][nt]);
    }
  }

  if (MODE == 0) {
    u16* op = (u16*)outp;
#pragma unroll
    for (int mt = 0; mt < 4; mt++) {
      int row0 = tile_m + wm * 64 + mt * 16 + quad * 4;
      int bb = row0 >> 12;
      int sbase = row0 & (S0 - 1);
#pragma unroll
      for (int nt = 0; nt < NT; nt++) {
        int col = tile_n + wn * (BN / 2) + nt * 16 + l16;
        int p = col >> 10;
        int rem = col & 1023;
        float bias = bf2f(cb[p * 1024 + rem]);
        int hh = rem >> 6, dd = rem & 63;
        u16* dp = op + ((size_t)(((p * 2 + bb) * NH + hh)) * S0 + sbase) * HD + dd;
#pragma unroll
        for (int r = 0; r < 4; r++)
          dp[(size_t)r * HD] = f2bf(acc[mt][nt][r] + bias);
      }
    }
  } else {
    float* op = (float*)outp;
#pragma unroll
    for (int mt = 0; mt < 4; mt++) {
      int row0 = tile_m + wm * 64 + mt * 16 + quad * 4;
#pragma unroll
      for (int nt = 0; nt < NT; nt++) {
        int col = tile_n + wn * (BN / 2) + nt * 16 + l16;
        float bias = bf2f(cb[3 * 1024 + col]);
        float* dp = op + (size_t)row0 * HID + col;
#pragma unroll
        for (int r = 0; r < 4; r++)
          dp[(size_t)r * HID] = acc[mt][nt][r] + bias;  // fp32 output
      }
    }
  }
}

// ---------------- windowed attention: one block per (b, h, chunk) ----------
// r0-exact form (the 153.7us-non-gemm0 config): stride 208 V^T, no Q-hoist,
// no setprio (4-wave lockstep = the regime where setprio measured negative).
__global__ __launch_bounds__(256) void attn_win(
    const u16* __restrict__ Q, const u16* __restrict__ Kp,
    const u16* __restrict__ Vp, const u16* __restrict__ cmask,
    u16* __restrict__ ctx) {
  __shared__ alignas(16) u16 buf0[208 * 64];   // phase1: K swizzled [slot][64]
                                               // phase2: V^T [d][208]
  __shared__ alignas(16) u16 sP[4 * 16 * 200]; // [wave][qrow][key 0..160)
  __shared__ u16 sMk[208];

  int bid = blockIdx.x;
  int c = bid & 63;
  int h = (bid >> 6) & 15;
  int b = bid >> 10;
  int t = threadIdx.x;
  int wave = t >> 6, lane = t & 63;
  int quad = lane >> 4, l16 = lane & 15;
  int koff = wave * 16;  // this wave's key-window start (rel kbase)

  const u16* Qb = Q + (size_t)(b * NH + h) * S0 * HD;
  const u16* Kb = Kp + (size_t)(b * NH + h) * S0 * HD;
  const u16* Vb = Vp + (size_t)(b * NH + h) * S0 * HD;
  int kbase = (c - 1) * 64;  // global key index of slot 0

  // ---- stage K via glds16, source-swizzled (chunk csrc -> LDS chunk l&7) --
  int rrow = lane >> 3;                 // row within the wave's 8-row group
  int csrc = ((lane & 7) ^ rrow) * 8;   // swizzled source chunk (elems)
#pragma unroll
  for (int p = 0; p < 7; p++) {
    int sl0 = p * 32 + wave * 8;        // wave-uniform row base (mult of 8)
    if (sl0 < 208) {
      int key = kbase + sl0 + rrow;
      int kc = key < 0 ? 0 : (key > S0 - 1 ? S0 - 1 : key);
      glds16(Kb + (size_t)kc * HD + csrc, buf0 + sl0 * 64);
    }
  }
  if (t < 208) {
    int j = kbase + t;
    sMk[t] = (j >= 0 && j < S0) ? cmask[(size_t)b * S0 + j] : (u16)0;
  }
  __syncthreads();

  // ---- QK from LDS: 9 key tiles cover the band exactly --------------------
  floatx4 sc[9] = {};
  int qrow = c * 64 + wave * 16 + l16;
#pragma unroll
  for (int ks = 0; ks < 2; ks++) {
    bf16x8 aq = *(const bf16x8*)(Qb + (size_t)qrow * HD + ks * 32 + quad * 8);
#pragma unroll
    for (int nt = 0; nt < 9; nt++) {
      int slot = koff + nt * 16 + l16;
      int pch = ((ks * 4 + quad) ^ (l16 & 7)) * 8;  // un-swizzle
      bf16x8 bk = *(const bf16x8*)(buf0 + slot * 64 + pch);
      sc[nt] = MFMA16(aq, bk, sc[nt]);
    }
  }

  // ---- preload V into registers (latency hides under softmax) -------------
  u16x8 vreg[7];
#pragma unroll
  for (int i = 0; i < 7; i++) {
    int e = i * 256 + t;  // 208*8 = 1664 tasks
    if (e < 1664) {
      int dg = e / 208;         // d block of 8
      int slot = e - dg * 208;  // 0..207
      int key = kbase + slot;
      int kc = key < 0 ? 0 : (key > S0 - 1 ? S0 - 1 : key);
      vreg[i] = *(const u16x8*)(Vb + (size_t)kc * HD + dg * 8);
    }
  }

  // ---- mask + softmax (rows across the 16 lanes of a quad) + write P ------
  int qrel_base = wave * 16 + quad * 4;
  u16* myP = sP + wave * 16 * 200;
  float kmask[9];
#pragma unroll
  for (int nt = 0; nt < 9; nt++) kmask[nt] = bf2f(sMk[koff + nt * 16 + l16]);

#pragma unroll
  for (int reg = 0; reg < 4; reg++) {
    int qrel = qrel_base + reg;
    float v[9];
    float m = -3e38f;
#pragma unroll
    for (int nt = 0; nt < 9; nt++) {
      int slot = koff + nt * 16 + l16;  // band: qrel <= slot <= qrel+128
      bool ok = (slot >= qrel) && (slot <= qrel + 128) && (kmask[nt] > 0.f);
      float s = ok ? sc[nt][reg] * 0.125f : -1e30f;
      v[nt] = s;
      m = fmaxf(m, s);
    }
#pragma unroll
    for (int off = 1; off <= 8; off <<= 1) m = fmaxf(m, __shfl_xor(m, off));
    float sum = 0.f;
#pragma unroll
    for (int nt = 0; nt < 9; nt++) {
      float p = __expf(v[nt] - m);
      v[nt] = p;
      sum += p;
    }
#pragma unroll
    for (int off = 1; off <= 8; off <<= 1) sum += __shfl_xor(sum, off);
    float inv = 1.0f / sum;
    int prow = (quad * 4 + reg) * 200;
#pragma unroll
    for (int nt = 0; nt < 9; nt++)
      myP[prow + nt * 16 + l16] = f2bf(v[nt] * inv);
    myP[prow + 144 + l16] = 0;  // zero-pad tile 9 -> P width 160
  }
  __syncthreads();  // all waves done reading K from buf0

  // ---- scatter V^T into buf0 ([d][key], stride 208) -----------------------
#pragma unroll
  for (int i = 0; i < 7; i++) {
    int e = i * 256 + t;
    if (e < 1664) {
      int dg = e / 208;
      int slot = e - dg * 208;
#pragma unroll
      for (int j = 0; j < 8; j++) buf0[(dg * 8 + j) * 208 + slot] = vreg[i][j];
    }
  }
  __syncthreads();

  // ---- PV over the 160-key padded window ----------------------------------
  floatx4 oc[4] = {};
#pragma unroll
  for (int ks = 0; ks < 5; ks++) {
    bf16x8 ap = *(const bf16x8*)(myP + l16 * 200 + ks * 32 + quad * 8);
#pragma unroll
    for (int nt = 0; nt < 4; nt++) {
      bf16x8 bv =
          *(const bf16x8*)(buf0 + (nt * 16 + l16) * 208 + koff + ks * 32 + quad * 8);
      oc[nt] = MFMA16(ap, bv, oc[nt]);
    }
  }

  int srow = c * 64 + wave * 16 + quad * 4;
#pragma unroll
  for (int nt = 0; nt < 4; nt++) {
    u16* dp = ctx + (size_t)(b * S0 + srow) * HID + h * HD + nt * 16 + l16;
#pragma unroll
    for (int reg = 0; reg < 4; reg++)
      dp[(size_t)reg * HID] = f2bf(oc[nt][reg]);
  }
}

// ---------------------------------------------------------------------------
extern "C" void kernel_launch(void* const* d_in, const int* in_sizes, int n_in,
                              void* d_out, int out_size, void* d_ws, size_t ws_size,
                              hipStream_t stream) {
  const float* X = (const float*)d_in[0];
  const float* mask = (const float*)d_in[1];
  const float* Wq = (const float*)d_in[2];
  const float* bq = (const float*)d_in[3];
  const float* Wk = (const float*)d_in[4];
  const float* bk = (const float*)d_in[5];
  const float* Wv = (const float*)d_in[6];
  const float* bv = (const float*)d_in[7];
  const float* Wo = (const float*)d_in[8];
  const float* bo = (const float*)d_in[9];
  char* ws = (char*)d_ws;

  const size_t MB = 1048576;
  u16* cmask = (u16*)(ws + 256);               // 16 KB
  u16* cb = (u16*)(ws + 256 + 16384);          // 8 KB
  u16* cX = (u16*)(ws + 1 * MB);               // 16 MB (CTX aliases after gemm0)
  u16* WqkvT = (u16*)(ws + 17 * MB);           // 6 MB
  u16* WoT = (u16*)(ws + 23 * MB);             // 2 MB
  u16* QKV = (u16*)(ws + 25 * MB);             // 48 MB
  u16* CTX = cX;                               // alias: cX dead after gemm0

  const size_t per_qkv = (size_t)B_ * NH * S0 * HD;  // elements per Q/K/V

  prep<<<4096 + 48 + 1024, 256, 0, stream>>>(X, mask, Wq, bq, Wk, bk, Wv, bv,
                                             Wo, bo, cX, cmask, cb, WqkvT, WoT);
  // gemm0: n-major (x = N-tiles) — measured 66.0 us
  gemm_bf16_tn<96, 0, 1><<<dim3(32, 64), 256, 0, stream>>>(cX, WqkvT, cb, QKV, HID);
  attn_win<<<dim3(B_ * NH * 64), 256, 0, stream>>>(QKV, QKV + per_qkv,
                                                   QKV + 2 * per_qkv, cmask, CTX);
  // gemm1: r0-proven m-major
  gemm_bf16_tn<128, 1, 0><<<dim3(64, 8), 256, 0, stream>>>(CTX, WoT, cb, d_out, HID);
}

// Round 7
// 221.136 us; speedup vs baseline: 1.0228x; 1.0228x over previous
//
#include <hip/hip_runtime.h>

typedef unsigned short u16;
typedef unsigned int u32;
typedef __bf16 bf16x8 __attribute__((ext_vector_type(8)));
typedef u16 u16x8 __attribute__((ext_vector_type(8)));
typedef float floatx4 __attribute__((ext_vector_type(4)));

#define MFMA16(a, b, c) __builtin_amdgcn_mfma_f32_16x16x32_bf16((a), (b), (c), 0, 0, 0)

#define B_ 2
#define S0 4096
#define NH 16
#define HD 64
#define HID 1024

__device__ __forceinline__ float bf2f(u16 u) {
  union { u32 i; float f; } x; x.i = ((u32)u) << 16; return x.f;
}
__device__ __forceinline__ u16 f2bf(float f) {
  union { float f; u32 i; } x; x.f = f;
  u32 r = x.i + 0x7FFFu + ((x.i >> 16) & 1u);
  return (u16)(r >> 16);
}

__device__ __forceinline__ void glds16(const u16* g, u16* l) {
  __builtin_amdgcn_global_load_lds(
      (const __attribute__((address_space(1))) u32*)g,
      (__attribute__((address_space(3))) u32*)l, 16, 0, 0);
}

// -------- fused prep: convert X, convert mask+biases, transpose weights -----
__global__ __launch_bounds__(256) void prep(
    const float* __restrict__ X, const float* __restrict__ mask,
    const float* __restrict__ Wq, const float* __restrict__ bq,
    const float* __restrict__ Wk, const float* __restrict__ bk,
    const float* __restrict__ Wv, const float* __restrict__ bv,
    const float* __restrict__ Wo, const float* __restrict__ bo,
    u16* __restrict__ cX, u16* __restrict__ cmask, u16* __restrict__ cb,
    u16* __restrict__ WqkvT, u16* __restrict__ WoT) {
  __shared__ u16 tile[64][66];
  int bid = blockIdx.x;
  if (bid < 4096) {                       // ---- X fp32 -> bf16 (8 elem/thr)
    int i = (bid * 256 + threadIdx.x) * 8;
    const float4* Xv = (const float4*)(X + i);
    float4 a = Xv[0], b = Xv[1];
    u16x8 v;
    v[0] = f2bf(a.x); v[1] = f2bf(a.y); v[2] = f2bf(a.z); v[3] = f2bf(a.w);
    v[4] = f2bf(b.x); v[5] = f2bf(b.y); v[6] = f2bf(b.z); v[7] = f2bf(b.w);
    *(u16x8*)(cX + i) = v;
  } else if (bid < 4144) {                // ---- mask + biases
    int tid = (bid - 4096) * 256 + threadIdx.x;
    if (tid < B_ * S0) {
      cmask[tid] = f2bf(mask[tid]);
    } else {
      int j = tid - B_ * S0;  // [0, 4096)
      int seg = j >> 10, idx = j & 1023;
      const float* src = (seg == 0) ? bq : (seg == 1) ? bk : (seg == 2) ? bv : bo;
      cb[seg * 1024 + idx] = f2bf(src[idx]);
    }
  } else {                                // ---- weight transpose (1024 blocks)
    int idx = bid - 4144;
    int mat = idx >> 8;
    const float* src = (mat == 0) ? Wq : (mat == 1) ? Wk : (mat == 2) ? Wv : Wo;
    u16* dst = (mat < 3) ? (WqkvT + (size_t)mat * HID * HID) : WoT;
    int t0 = ((idx >> 4) & 15) * 64;  // k base
    int c0 = (idx & 15) * 64;         // n base
    int tx = threadIdx.x & 63, ty = threadIdx.x >> 6;
#pragma unroll
    for (int i = 0; i < 16; i++) {
      int r = i * 4 + ty;
      tile[r][tx] = f2bf(src[(size_t)(t0 + r) * HID + c0 + tx]);
    }
    __syncthreads();
#pragma unroll
    for (int i = 0; i < 16; i++) {
      int r = i * 4 + ty;
      dst[(size_t)(c0 + r) * HID + t0 + tx] = tile[tx][r];
    }
  }
}

// ---------------- bf16 GEMM: C[m][n] = A[m][k] * Bt[n][k] + bias -----------
// BK=64, glds16 staging, 16B-chunk XOR swizzle -> conflict-free ds_read_b128.
// SWZ=1 (gemm0, grid 32x64=2048): XCD-chunked n-major remap — each XCD owns
// 8 contiguous m-panels (A 2MB stays L2-hot); co-resident y-rows share B
// tiles in L2. SWZ=0 NMAJOR=0 (gemm1): r0-proven m-major.
template <int BN, int MODE, int NMAJOR, int SWZ>
__global__ __launch_bounds__(256) void gemm_bf16_tn(
    const u16* __restrict__ A, const u16* __restrict__ Bt,
    const u16* __restrict__ cb, void* __restrict__ outp, int K) {
  constexpr int NT = BN / 32;  // 16-col tiles per wave (wave covers BN/2 cols)
  __shared__ alignas(16) u16 sA[128 * 64];
  __shared__ alignas(16) u16 sB[BN * 64];
  int t = threadIdx.x;
  int wave = t >> 6, lane = t & 63;
  int wm = wave >> 1, wn = wave & 1;
  int quad = lane >> 4, l16 = lane & 15;
  int tile_m, tile_n;
  if (SWZ) {
    // dispatch index (x fastest) -> XCD-chunked bijection (2048 = 8*256)
    int lin = blockIdx.y * gridDim.x + blockIdx.x;
    int wg = (lin & 7) * 256 + (lin >> 3);
    tile_m = (wg >> 5) * 128;   // y-major within chunk: 8 m-panels per XCD
    tile_n = (wg & 31) * BN;
  } else {
    tile_m = (NMAJOR ? blockIdx.y : blockIdx.x) * 128;
    tile_n = (NMAJOR ? blockIdx.x : blockIdx.y) * BN;
  }

  floatx4 acc[4][NT] = {};

  int row_l = lane >> 3;
  int col_l = ((lane & 7) ^ row_l) * 8;
  const u16* Ag = A + (size_t)(tile_m + wave * 8 + row_l) * K + col_l;
  const u16* Bg = Bt + (size_t)(tile_n + wave * 8 + row_l) * K + col_l;
  u16* lA = sA + wave * 8 * 64;
  u16* lB = sB + wave * 8 * 64;

  for (int k0 = 0; k0 < K; k0 += 64) {
    __syncthreads();
#pragma unroll
    for (int r = 0; r < 4; r++)
      glds16(Ag + (size_t)(r * 32) * K + k0, lA + r * 2048);
#pragma unroll
    for (int r = 0; r < BN / 32; r++)
      glds16(Bg + (size_t)(r * 32) * K + k0, lB + r * 2048);
    __syncthreads();

#pragma unroll
    for (int ks = 0; ks < 2; ks++) {
      bf16x8 af[4], bfr[NT];
#pragma unroll
      for (int mt = 0; mt < 4; mt++) {
        int row = wm * 64 + mt * 16 + l16;
        int p = (ks * 4 + quad) ^ (row & 7);
        af[mt] = *(const bf16x8*)(sA + row * 64 + p * 8);
      }
#pragma unroll
      for (int nt = 0; nt < NT; nt++) {
        int row = wn * (BN / 2) + nt * 16 + l16;
        int p = (ks * 4 + quad) ^ (row & 7);
        bfr[nt] = *(const bf16x8*)(sB + row * 64 + p * 8);
      }
#pragma unroll
      for (int mt = 0; mt < 4; mt++)
#pragma unroll
        for (int nt = 0; nt < NT; nt++)
          acc[mt][nt] = MFMA16(af[mt], bfr[nt], acc[mt][nt]);
    }
  }

  if (MODE == 0) {
    u16* op = (u16*)outp;
#pragma unroll
    for (int mt = 0; mt < 4; mt++) {
      int row0 = tile_m + wm * 64 + mt * 16 + quad * 4;
      int bb = row0 >> 12;
      int sbase = row0 & (S0 - 1);
#pragma unroll
      for (int nt = 0; nt < NT; nt++) {
        int col = tile_n + wn * (BN / 2) + nt * 16 + l16;
        int p = col >> 10;
        int rem = col & 1023;
        float bias = bf2f(cb[p * 1024 + rem]);
        int hh = rem >> 6, dd = rem & 63;
        u16* dp = op + ((size_t)(((p * 2 + bb) * NH + hh)) * S0 + sbase) * HD + dd;
#pragma unroll
        for (int r = 0; r < 4; r++)
          dp[(size_t)r * HD] = f2bf(acc[mt][nt][r] + bias);
      }
    }
  } else {
    float* op = (float*)outp;
#pragma unroll
    for (int mt = 0; mt < 4; mt++) {
      int row0 = tile_m + wm * 64 + mt * 16 + quad * 4;
#pragma unroll
      for (int nt = 0; nt < NT; nt++) {
        int col = tile_n + wn * (BN / 2) + nt * 16 + l16;
        float bias = bf2f(cb[3 * 1024 + col]);
        float* dp = op + (size_t)row0 * HID + col;
#pragma unroll
        for (int r = 0; r < 4; r++)
          dp[(size_t)r * HID] = acc[mt][nt][r] + bias;  // fp32 output
      }
    }
  }
}

// ---------------- windowed attention: one block per (b, h, chunk) ----------
// r0-proven inner structure. NEW: XCD-chunked bid swizzle (2048 = 8*256) so
// adjacent chunks of the same head run on the SAME XCD — the 144/208-key
// overlap between neighboring chunks becomes L2 hits instead of L3 refetch
// (each key is staged 3.25x; working set ~3MB < 4MiB XCD-L2).
__global__ __launch_bounds__(256) void attn_win(
    const u16* __restrict__ Q, const u16* __restrict__ Kp,
    const u16* __restrict__ Vp, const u16* __restrict__ cmask,
    u16* __restrict__ ctx) {
  __shared__ alignas(16) u16 buf0[208 * 64];   // phase1: K swizzled [slot][64]
                                               // phase2: V^T [d][208]
  __shared__ alignas(16) u16 sP[4 * 16 * 200]; // [wave][qrow][key 0..160)
  __shared__ u16 sMk[208];

  int lin = blockIdx.x;
  int bid = (lin & 7) * 256 + (lin >> 3);  // bijective XCD chunking
  int c = bid & 63;
  int h = (bid >> 6) & 15;
  int b = bid >> 10;
  int t = threadIdx.x;
  int wave = t >> 6, lane = t & 63;
  int quad = lane >> 4, l16 = lane & 15;
  int koff = wave * 16;  // this wave's key-window start (rel kbase)

  const u16* Qb = Q + (size_t)(b * NH + h) * S0 * HD;
  const u16* Kb = Kp + (size_t)(b * NH + h) * S0 * HD;
  const u16* Vb = Vp + (size_t)(b * NH + h) * S0 * HD;
  int kbase = (c - 1) * 64;  // global key index of slot 0

  // ---- stage K via glds16, source-swizzled (chunk csrc -> LDS chunk l&7) --
  int rrow = lane >> 3;                 // row within the wave's 8-row group
  int csrc = ((lane & 7) ^ rrow) * 8;   // swizzled source chunk (elems)
#pragma unroll
  for (int p = 0; p < 7; p++) {
    int sl0 = p * 32 + wave * 8;        // wave-uniform row base (mult of 8)
    if (sl0 < 208) {
      int key = kbase + sl0 + rrow;
      int kc = key < 0 ? 0 : (key > S0 - 1 ? S0 - 1 : key);
      glds16(Kb + (size_t)kc * HD + csrc, buf0 + sl0 * 64);
    }
  }
  if (t < 208) {
    int j = kbase + t;
    sMk[t] = (j >= 0 && j < S0) ? cmask[(size_t)b * S0 + j] : (u16)0;
  }
  __syncthreads();

  // ---- QK from LDS: 9 key tiles cover the band exactly --------------------
  floatx4 sc[9] = {};
  int qrow = c * 64 + wave * 16 + l16;
#pragma unroll
  for (int ks = 0; ks < 2; ks++) {
    bf16x8 aq = *(const bf16x8*)(Qb + (size_t)qrow * HD + ks * 32 + quad * 8);
#pragma unroll
    for (int nt = 0; nt < 9; nt++) {
      int slot = koff + nt * 16 + l16;
      int pch = ((ks * 4 + quad) ^ (l16 & 7)) * 8;  // un-swizzle
      bf16x8 bk = *(const bf16x8*)(buf0 + slot * 64 + pch);
      sc[nt] = MFMA16(aq, bk, sc[nt]);
    }
  }

  // ---- preload V into registers (latency hides under softmax) -------------
  u16x8 vreg[7];
#pragma unroll
  for (int i = 0; i < 7; i++) {
    int e = i * 256 + t;  // 208*8 = 1664 tasks
    if (e < 1664) {
      int dg = e / 208;         // d block of 8
      int slot = e - dg * 208;  // 0..207
      int key = kbase + slot;
      int kc = key < 0 ? 0 : (key > S0 - 1 ? S0 - 1 : key);
      vreg[i] = *(const u16x8*)(Vb + (size_t)kc * HD + dg * 8);
    }
  }

  // ---- mask + softmax (rows across the 16 lanes of a quad) + write P ------
  int qrel_base = wave * 16 + quad * 4;
  u16* myP = sP + wave * 16 * 200;
  float kmask[9];
#pragma unroll
  for (int nt = 0; nt < 9; nt++) kmask[nt] = bf2f(sMk[koff + nt * 16 + l16]);

#pragma unroll
  for (int reg = 0; reg < 4; reg++) {
    int qrel = qrel_base + reg;
    float v[9];
    float m = -3e38f;
#pragma unroll
    for (int nt = 0; nt < 9; nt++) {
      int slot = koff + nt * 16 + l16;  // band: qrel <= slot <= qrel+128
      bool ok = (slot >= qrel) && (slot <= qrel + 128) && (kmask[nt] > 0.f);
      float s = ok ? sc[nt][reg] * 0.125f : -1e30f;
      v[nt] = s;
      m = fmaxf(m, s);
    }
#pragma unroll
    for (int off = 1; off <= 8; off <<= 1) m = fmaxf(m, __shfl_xor(m, off));
    float sum = 0.f;
#pragma unroll
    for (int nt = 0; nt < 9; nt++) {
      float p = __expf(v[nt] - m);
      v[nt] = p;
      sum += p;
    }
#pragma unroll
    for (int off = 1; off <= 8; off <<= 1) sum += __shfl_xor(sum, off);
    float inv = 1.0f / sum;
    int prow = (quad * 4 + reg) * 200;
#pragma unroll
    for (int nt = 0; nt < 9; nt++)
      myP[prow + nt * 16 + l16] = f2bf(v[nt] * inv);
    myP[prow + 144 + l16] = 0;  // zero-pad tile 9 -> P width 160
  }
  __syncthreads();  // all waves done reading K from buf0

  // ---- scatter V^T into buf0 ([d][key], stride 208) -----------------------
#pragma unroll
  for (int i = 0; i < 7; i++) {
    int e = i * 256 + t;
    if (e < 1664) {
      int dg = e / 208;
      int slot = e - dg * 208;
#pragma unroll
      for (int j = 0; j < 8; j++) buf0[(dg * 8 + j) * 208 + slot] = vreg[i][j];
    }
  }
  __syncthreads();

  // ---- PV over the 160-key padded window ----------------------------------
  floatx4 oc[4] = {};
#pragma unroll
  for (int ks = 0; ks < 5; ks++) {
    bf16x8 ap = *(const bf16x8*)(myP + l16 * 200 + ks * 32 + quad * 8);
#pragma unroll
    for (int nt = 0; nt < 4; nt++) {
      bf16x8 bv =
          *(const bf16x8*)(buf0 + (nt * 16 + l16) * 208 + koff + ks * 32 + quad * 8);
      oc[nt] = MFMA16(ap, bv, oc[nt]);
    }
  }

  int srow = c * 64 + wave * 16 + quad * 4;
#pragma unroll
  for (int nt = 0; nt < 4; nt++) {
    u16* dp = ctx + (size_t)(b * S0 + srow) * HID + h * HD + nt * 16 + l16;
#pragma unroll
    for (int reg = 0; reg < 4; reg++)
      dp[(size_t)reg * HID] = f2bf(oc[nt][reg]);
  }
}

// ---------------------------------------------------------------------------
extern "C" void kernel_launch(void* const* d_in, const int* in_sizes, int n_in,
                              void* d_out, int out_size, void* d_ws, size_t ws_size,
                              hipStream_t stream) {
  const float* X = (const float*)d_in[0];
  const float* mask = (const float*)d_in[1];
  const float* Wq = (const float*)d_in[2];
  const float* bq = (const float*)d_in[3];
  const float* Wk = (const float*)d_in[4];
  const float* bk = (const float*)d_in[5];
  const float* Wv = (const float*)d_in[6];
  const float* bv = (const float*)d_in[7];
  const float* Wo = (const float*)d_in[8];
  const float* bo = (const float*)d_in[9];
  char* ws = (char*)d_ws;

  const size_t MB = 1048576;
  u16* cmask = (u16*)(ws + 256);               // 16 KB
  u16* cb = (u16*)(ws + 256 + 16384);          // 8 KB
  u16* cX = (u16*)(ws + 1 * MB);               // 16 MB (CTX aliases after gemm0)
  u16* WqkvT = (u16*)(ws + 17 * MB);           // 6 MB
  u16* WoT = (u16*)(ws + 23 * MB);             // 2 MB
  u16* QKV = (u16*)(ws + 25 * MB);             // 48 MB
  u16* CTX = cX;                               // alias: cX dead after gemm0

  const size_t per_qkv = (size_t)B_ * NH * S0 * HD;  // elements per Q/K/V

  prep<<<4096 + 48 + 1024, 256, 0, stream>>>(X, mask, Wq, bq, Wk, bk, Wv, bv,
                                             Wo, bo, cX, cmask, cb, WqkvT, WoT);
  // gemm0: XCD-chunked n-major swizzle
  gemm_bf16_tn<96, 0, 1, 1><<<dim3(32, 64), 256, 0, stream>>>(cX, WqkvT, cb, QKV, HID);
  attn_win<<<dim3(B_ * NH * 64), 256, 0, stream>>>(QKV, QKV + per_qkv,
                                                   QKV + 2 * per_qkv, cmask, CTX);
  // gemm1: r0-proven m-major, no swizzle
  gemm_bf16_tn<128, 1, 0, 0><<<dim3(64, 8), 256, 0, stream>>>(CTX, WoT, cb, d_out, HID);
}

// Round 8
// 220.264 us; speedup vs baseline: 1.0268x; 1.0040x over previous
//
#include <hip/hip_runtime.h>

typedef unsigned short u16;
typedef unsigned int u32;
typedef __bf16 bf16x8 __attribute__((ext_vector_type(8)));
typedef u16 u16x8 __attribute__((ext_vector_type(8)));
typedef float floatx4 __attribute__((ext_vector_type(4)));

#define MFMA16(a, b, c) __builtin_amdgcn_mfma_f32_16x16x32_bf16((a), (b), (c), 0, 0, 0)

#define B_ 2
#define S0 4096
#define NH 16
#define HD 64
#define HID 1024
#define VS 280   // V^T row stride (u16): mult of 8 (16B align), 140dw%32=12 -> 2-way free
#define PS 200   // P row stride (u16)

__device__ __forceinline__ float bf2f(u16 u) {
  union { u32 i; float f; } x; x.i = ((u32)u) << 16; return x.f;
}
__device__ __forceinline__ u16 f2bf(float f) {
  union { float f; u32 i; } x; x.f = f;
  u32 r = x.i + 0x7FFFu + ((x.i >> 16) & 1u);
  return (u16)(r >> 16);
}

__device__ __forceinline__ void glds16(const u16* g, u16* l) {
  __builtin_amdgcn_global_load_lds(
      (const __attribute__((address_space(1))) u32*)g,
      (__attribute__((address_space(3))) u32*)l, 16, 0, 0);
}

// -------- fused prep: convert X, convert mask+biases, transpose weights -----
__global__ __launch_bounds__(256) void prep(
    const float* __restrict__ X, const float* __restrict__ mask,
    const float* __restrict__ Wq, const float* __restrict__ bq,
    const float* __restrict__ Wk, const float* __restrict__ bk,
    const float* __restrict__ Wv, const float* __restrict__ bv,
    const float* __restrict__ Wo, const float* __restrict__ bo,
    u16* __restrict__ cX, u16* __restrict__ cmask, u16* __restrict__ cb,
    u16* __restrict__ WqkvT, u16* __restrict__ WoT) {
  __shared__ u16 tile[64][66];
  int bid = blockIdx.x;
  if (bid < 4096) {                       // ---- X fp32 -> bf16 (8 elem/thr)
    int i = (bid * 256 + threadIdx.x) * 8;
    const float4* Xv = (const float4*)(X + i);
    float4 a = Xv[0], b = Xv[1];
    u16x8 v;
    v[0] = f2bf(a.x); v[1] = f2bf(a.y); v[2] = f2bf(a.z); v[3] = f2bf(a.w);
    v[4] = f2bf(b.x); v[5] = f2bf(b.y); v[6] = f2bf(b.z); v[7] = f2bf(b.w);
    *(u16x8*)(cX + i) = v;
  } else if (bid < 4144) {                // ---- mask + biases
    int tid = (bid - 4096) * 256 + threadIdx.x;
    if (tid < B_ * S0) {
      cmask[tid] = f2bf(mask[tid]);
    } else {
      int j = tid - B_ * S0;  // [0, 4096)
      int seg = j >> 10, idx = j & 1023;
      const float* src = (seg == 0) ? bq : (seg == 1) ? bk : (seg == 2) ? bv : bo;
      cb[seg * 1024 + idx] = f2bf(src[idx]);
    }
  } else {                                // ---- weight transpose (1024 blocks)
    int idx = bid - 4144;
    int mat = idx >> 8;
    const float* src = (mat == 0) ? Wq : (mat == 1) ? Wk : (mat == 2) ? Wv : Wo;
    u16* dst = (mat < 3) ? (WqkvT + (size_t)mat * HID * HID) : WoT;
    int t0 = ((idx >> 4) & 15) * 64;  // k base
    int c0 = (idx & 15) * 64;         // n base
    int tx = threadIdx.x & 63, ty = threadIdx.x >> 6;
#pragma unroll
    for (int i = 0; i < 16; i++) {
      int r = i * 4 + ty;
      tile[r][tx] = f2bf(src[(size_t)(t0 + r) * HID + c0 + tx]);
    }
    __syncthreads();
#pragma unroll
    for (int i = 0; i < 16; i++) {
      int r = i * 4 + ty;
      dst[(size_t)(c0 + r) * HID + t0 + tx] = tile[tx][r];
    }
  }
}

// ---------------- bf16 GEMM: C[m][n] = A[m][k] * Bt[n][k] + bias -----------
// BK=64, glds16 staging, 16B-chunk XOR swizzle -> conflict-free ds_read_b128.
// SWZ=1 (gemm0): XCD-chunked n-major remap (r7-measured best-total config).
template <int BN, int MODE, int NMAJOR, int SWZ>
__global__ __launch_bounds__(256) void gemm_bf16_tn(
    const u16* __restrict__ A, const u16* __restrict__ Bt,
    const u16* __restrict__ cb, void* __restrict__ outp, int K) {
  constexpr int NT = BN / 32;  // 16-col tiles per wave (wave covers BN/2 cols)
  __shared__ alignas(16) u16 sA[128 * 64];
  __shared__ alignas(16) u16 sB[BN * 64];
  int t = threadIdx.x;
  int wave = t >> 6, lane = t & 63;
  int wm = wave >> 1, wn = wave & 1;
  int quad = lane >> 4, l16 = lane & 15;
  int tile_m, tile_n;
  if (SWZ) {
    // dispatch index (x fastest) -> XCD-chunked bijection (2048 = 8*256)
    int lin = blockIdx.y * gridDim.x + blockIdx.x;
    int wg = (lin & 7) * 256 + (lin >> 3);
    tile_m = (wg >> 5) * 128;   // y-major within chunk: 8 m-panels per XCD
    tile_n = (wg & 31) * BN;
  } else {
    tile_m = (NMAJOR ? blockIdx.y : blockIdx.x) * 128;
    tile_n = (NMAJOR ? blockIdx.x : blockIdx.y) * BN;
  }

  floatx4 acc[4][NT] = {};

  int row_l = lane >> 3;
  int col_l = ((lane & 7) ^ row_l) * 8;
  const u16* Ag = A + (size_t)(tile_m + wave * 8 + row_l) * K + col_l;
  const u16* Bg = Bt + (size_t)(tile_n + wave * 8 + row_l) * K + col_l;
  u16* lA = sA + wave * 8 * 64;
  u16* lB = sB + wave * 8 * 64;

  for (int k0 = 0; k0 < K; k0 += 64) {
    __syncthreads();
#pragma unroll
    for (int r = 0; r < 4; r++)
      glds16(Ag + (size_t)(r * 32) * K + k0, lA + r * 2048);
#pragma unroll
    for (int r = 0; r < BN / 32; r++)
      glds16(Bg + (size_t)(r * 32) * K + k0, lB + r * 2048);
    __syncthreads();

#pragma unroll
    for (int ks = 0; ks < 2; ks++) {
      bf16x8 af[4], bfr[NT];
#pragma unroll
      for (int mt = 0; mt < 4; mt++) {
        int row = wm * 64 + mt * 16 + l16;
        int p = (ks * 4 + quad) ^ (row & 7);
        af[mt] = *(const bf16x8*)(sA + row * 64 + p * 8);
      }
#pragma unroll
      for (int nt = 0; nt < NT; nt++) {
        int row = wn * (BN / 2) + nt * 16 + l16;
        int p = (ks * 4 + quad) ^ (row & 7);
        bfr[nt] = *(const bf16x8*)(sB + row * 64 + p * 8);
      }
#pragma unroll
      for (int mt = 0; mt < 4; mt++)
#pragma unroll
        for (int nt = 0; nt < NT; nt++)
          acc[mt][nt] = MFMA16(af[mt], bfr[nt], acc[mt][nt]);
    }
  }

  if (MODE == 0) {
    u16* op = (u16*)outp;
#pragma unroll
    for (int mt = 0; mt < 4; mt++) {
      int row0 = tile_m + wm * 64 + mt * 16 + quad * 4;
      int bb = row0 >> 12;
      int sbase = row0 & (S0 - 1);
#pragma unroll
      for (int nt = 0; nt < NT; nt++) {
        int col = tile_n + wn * (BN / 2) + nt * 16 + l16;
        int p = col >> 10;
        int rem = col & 1023;
        float bias = bf2f(cb[p * 1024 + rem]);
        int hh = rem >> 6, dd = rem & 63;
        u16* dp = op + ((size_t)(((p * 2 + bb) * NH + hh)) * S0 + sbase) * HD + dd;
#pragma unroll
        for (int r = 0; r < 4; r++)
          dp[(size_t)r * HD] = f2bf(acc[mt][nt][r] + bias);
      }
    }
  } else {
    float* op = (float*)outp;
#pragma unroll
    for (int mt = 0; mt < 4; mt++) {
      int row0 = tile_m + wm * 64 + mt * 16 + quad * 4;
#pragma unroll
      for (int nt = 0; nt < NT; nt++) {
        int col = tile_n + wn * (BN / 2) + nt * 16 + l16;
        float bias = bf2f(cb[3 * 1024 + col]);
        float* dp = op + (size_t)row0 * HID + col;
#pragma unroll
        for (int r = 0; r < 4; r++)
          dp[(size_t)r * HID] = acc[mt][nt][r] + bias;  // fp32 output
      }
    }
  }
}

// ------------- windowed attention: one block per (b, h, chunk-PAIR) --------
// Block handles chunks (2cc, 2cc+1) = 128 queries; combined key window is
// exactly 4 chunks = 256 slots (kbase = (2cc-1)*64). K/V staged ONCE for both
// chunks (per-key staging 3.25x -> 2.1x), one V^T scatter, 4 barriers per
// 2 chunks (was 6). Schedule: QK-A, softmax-A->sP, QK-B (K live), bar,
// scatter V^T, bar, PV-A, softmax-B->sP (wave-private reuse), PV-B.
// Chunk A uses slots [koff, koff+144), chunk B the same +64.
// LDS 62 KB -> 2 blk/CU.
__global__ __launch_bounds__(256) void attn_win2(
    const u16* __restrict__ Q, const u16* __restrict__ Kp,
    const u16* __restrict__ Vp, const u16* __restrict__ cmask,
    u16* __restrict__ ctx) {
  __shared__ alignas(16) u16 buf0[64 * VS];    // K [256][64] swz, then V^T [64][VS]
  __shared__ alignas(16) u16 sP[4 * 16 * PS];  // per-wave [16 q][key 0..160)
  __shared__ u16 sMk[256];

  int bid = blockIdx.x;            // 0..1023
  int cc = bid & 31, h = (bid >> 5) & 15, b = bid >> 9;
  int c0 = cc * 2;
  int t = threadIdx.x;
  int wave = t >> 6, lane = t & 63;
  int quad = lane >> 4, l16 = lane & 15;
  int koff = wave * 16;

  const u16* Qb = Q + (size_t)(b * NH + h) * S0 * HD;
  const u16* Kb = Kp + (size_t)(b * NH + h) * S0 * HD;
  const u16* Vb = Vp + (size_t)(b * NH + h) * S0 * HD;
  int kbase = (c0 - 1) * 64;  // global key of slot 0

  // ---- stage K: 256 slots via glds16, source-swizzled ---------------------
  int rrow = lane >> 3;
  int csrc = ((lane & 7) ^ rrow) * 8;
#pragma unroll
  for (int p = 0; p < 8; p++) {
    int sl0 = p * 32 + wave * 8;
    int key = kbase + sl0 + rrow;
    int kc = key < 0 ? 0 : (key > S0 - 1 ? S0 - 1 : key);
    glds16(Kb + (size_t)kc * HD + csrc, buf0 + sl0 * 64);
  }
  {
    int j = kbase + t;
    sMk[t] = (j >= 0 && j < S0) ? cmask[(size_t)b * S0 + j] : (u16)0;
  }
  __syncthreads();

  // ---- QK chunk A ---------------------------------------------------------
  floatx4 sc[9] = {};
  int qrowA = c0 * 64 + wave * 16 + l16;
#pragma unroll
  for (int ks = 0; ks < 2; ks++) {
    bf16x8 aq = *(const bf16x8*)(Qb + (size_t)qrowA * HD + ks * 32 + quad * 8);
#pragma unroll
    for (int nt = 0; nt < 9; nt++) {
      int slot = koff + nt * 16 + l16;
      int pch = ((ks * 4 + quad) ^ (l16 & 7)) * 8;
      bf16x8 bk = *(const bf16x8*)(buf0 + slot * 64 + pch);
      sc[nt] = MFMA16(aq, bk, sc[nt]);
    }
  }

  // ---- V preload: 272 slots x 8 dgroups = 2176 tasks (hides under softmax)
  u16x8 vreg[9];
#pragma unroll
  for (int i = 0; i < 9; i++) {
    int e = i * 256 + t;
    if (e < 2176) {
      int dg = e / 272;
      int slot = e - dg * 272;
      int key = kbase + slot;
      int kc = key < 0 ? 0 : (key > S0 - 1 ? S0 - 1 : key);
      vreg[i] = *(const u16x8*)(Vb + (size_t)kc * HD + dg * 8);
    }
  }

  u16* myP = sP + wave * 16 * PS;

#define SOFTMAX_P(off)                                                       \
  do {                                                                       \
    float kmask[9];                                                          \
    _Pragma("unroll") for (int nt = 0; nt < 9; nt++)                         \
        kmask[nt] = bf2f(sMk[(off) + koff + nt * 16 + l16]);                 \
    _Pragma("unroll") for (int reg = 0; reg < 4; reg++) {                    \
      int qrel = (off) + wave * 16 + quad * 4 + reg;                         \
      float v[9];                                                            \
      float m = -3e38f;                                                      \
      _Pragma("unroll") for (int nt = 0; nt < 9; nt++) {                     \
        int slot = (off) + koff + nt * 16 + l16;                             \
        bool ok = (slot >= qrel) && (slot <= qrel + 128) && (kmask[nt] > 0.f); \
        float s = ok ? sc[nt][reg] * 0.125f : -1e30f;                        \
        v[nt] = s;                                                           \
        m = fmaxf(m, s);                                                     \
      }                                                                      \
      _Pragma("unroll") for (int o2 = 1; o2 <= 8; o2 <<= 1)                  \
          m = fmaxf(m, __shfl_xor(m, o2));                                   \
      float sum = 0.f;                                                       \
      _Pragma("unroll") for (int nt = 0; nt < 9; nt++) {                     \
        float pp = __expf(v[nt] - m);                                        \
        v[nt] = pp;                                                          \
        sum += pp;                                                           \
      }                                                                      \
      _Pragma("unroll") for (int o2 = 1; o2 <= 8; o2 <<= 1)                  \
          sum += __shfl_xor(sum, o2);                                        \
      float inv = 1.0f / sum;                                                \
      int prow = (quad * 4 + reg) * PS;                                      \
      _Pragma("unroll") for (int nt = 0; nt < 9; nt++)                       \
          myP[prow + nt * 16 + l16] = f2bf(v[nt] * inv);                     \
      myP[prow + 144 + l16] = 0;                                             \
    }                                                                        \
  } while (0)

#define PV_CTX(off)                                                          \
  do {                                                                       \
    floatx4 oc[4] = {};                                                      \
    _Pragma("unroll") for (int ks = 0; ks < 5; ks++) {                       \
      bf16x8 ap = *(const bf16x8*)(myP + l16 * PS + ks * 32 + quad * 8);     \
      _Pragma("unroll") for (int nt = 0; nt < 4; nt++) {                     \
        bf16x8 bv = *(const bf16x8*)(buf0 + (nt * 16 + l16) * VS + (off) +   \
                                     koff + ks * 32 + quad * 8);             \
        oc[nt] = MFMA16(ap, bv, oc[nt]);                                     \
      }                                                                      \
    }                                                                        \
    int srow = c0 * 64 + (off) + wave * 16 + quad * 4;                       \
    _Pragma("unroll") for (int nt = 0; nt < 4; nt++) {                       \
      u16* dp = ctx + (size_t)(b * S0 + srow) * HID + h * HD + nt * 16 + l16; \
      _Pragma("unroll") for (int reg = 0; reg < 4; reg++)                    \
          dp[(size_t)reg * HID] = f2bf(oc[nt][reg]);                         \
    }                                                                        \
  } while (0)

  // softmax A -> sP (sc consumed, freed for B)
  SOFTMAX_P(0);

  // ---- QK chunk B (K still in buf0), slots +64 ----------------------------
#pragma unroll
  for (int nt = 0; nt < 9; nt++) sc[nt] = (floatx4){0.f, 0.f, 0.f, 0.f};
  int qrowB = qrowA + 64;
#pragma unroll
  for (int ks = 0; ks < 2; ks++) {
    bf16x8 aq = *(const bf16x8*)(Qb + (size_t)qrowB * HD + ks * 32 + quad * 8);
#pragma unroll
    for (int nt = 0; nt < 9; nt++) {
      int slot = 64 + koff + nt * 16 + l16;
      int pch = ((ks * 4 + quad) ^ (l16 & 7)) * 8;
      bf16x8 bk = *(const bf16x8*)(buf0 + slot * 64 + pch);
      sc[nt] = MFMA16(aq, bk, sc[nt]);
    }
  }
  __syncthreads();  // all QK reads of K done

  // ---- scatter V^T into buf0 ([d][slot], stride VS) -----------------------
#pragma unroll
  for (int i = 0; i < 9; i++) {
    int e = i * 256 + t;
    if (e < 2176) {
      int dg = e / 272;
      int slot = e - dg * 272;
#pragma unroll
      for (int j = 0; j < 8; j++) buf0[(dg * 8 + j) * VS + slot] = vreg[i][j];
    }
  }
  __syncthreads();  // V^T ready

  PV_CTX(0);        // chunk A: uses sP(A) written before QK-B
  SOFTMAX_P(64);    // chunk B: sc(B) -> sP (wave-private overwrite, no barrier)
  PV_CTX(64);       // chunk B
#undef SOFTMAX_P
#undef PV_CTX
}

// ---------------------------------------------------------------------------
extern "C" void kernel_launch(void* const* d_in, const int* in_sizes, int n_in,
                              void* d_out, int out_size, void* d_ws, size_t ws_size,
                              hipStream_t stream) {
  const float* X = (const float*)d_in[0];
  const float* mask = (const float*)d_in[1];
  const float* Wq = (const float*)d_in[2];
  const float* bq = (const float*)d_in[3];
  const float* Wk = (const float*)d_in[4];
  const float* bk = (const float*)d_in[5];
  const float* Wv = (const float*)d_in[6];
  const float* bv = (const float*)d_in[7];
  const float* Wo = (const float*)d_in[8];
  const float* bo = (const float*)d_in[9];
  char* ws = (char*)d_ws;

  const size_t MB = 1048576;
  u16* cmask = (u16*)(ws + 256);               // 16 KB
  u16* cb = (u16*)(ws + 256 + 16384);          // 8 KB
  u16* cX = (u16*)(ws + 1 * MB);               // 16 MB (CTX aliases after gemm0)
  u16* WqkvT = (u16*)(ws + 17 * MB);           // 6 MB
  u16* WoT = (u16*)(ws + 23 * MB);             // 2 MB
  u16* QKV = (u16*)(ws + 25 * MB);             // 48 MB
  u16* CTX = cX;                               // alias: cX dead after gemm0

  const size_t per_qkv = (size_t)B_ * NH * S0 * HD;  // elements per Q/K/V

  prep<<<4096 + 48 + 1024, 256, 0, stream>>>(X, mask, Wq, bq, Wk, bk, Wv, bv,
                                             Wo, bo, cX, cmask, cb, WqkvT, WoT);
  // gemm0: XCD-chunked n-major swizzle (r7 best-total config)
  gemm_bf16_tn<96, 0, 1, 1><<<dim3(32, 64), 256, 0, stream>>>(cX, WqkvT, cb, QKV, HID);
  // attn: chunk-paired, 1024 blocks
  attn_win2<<<dim3(B_ * NH * 32), 256, 0, stream>>>(QKV, QKV + per_qkv,
                                                    QKV + 2 * per_qkv, cmask, CTX);
  // gemm1: r0-proven m-major, no swizzle
  gemm_bf16_tn<128, 1, 0, 0><<<dim3(64, 8), 256, 0, stream>>>(CTX, WoT, cb, d_out, HID);
}